// Round 16
// baseline (85.982 us; speedup 1.0000x reference)
//
#include <hip/hip_runtime.h>
#include <hip/hip_bf16.h>

#define NB 4
#define NQ 1024
#define NKS 1024
#define ND 256
#define NH 8
#define NHD 32
#define NOUT 256
#define SPLIT 4

typedef __attribute__((ext_vector_type(8))) short v8s;
typedef __attribute__((ext_vector_type(4))) short v4s;
typedef __attribute__((ext_vector_type(4))) float f32x4;

// ---------------- prep: weight transpose -> bf16 [out][d] (5 matrices) ----------------
__global__ __launch_bounds__(256) void prep_w(
    const float* __restrict__ qw, const float* __restrict__ kw,
    const float* __restrict__ vw, const float* __restrict__ gw,
    const float* __restrict__ ow, __hip_bfloat16* __restrict__ Wt)
{
  __shared__ float tile[64][65];
  const int wb = blockIdx.x;                 // 0..79
  const int m = wb >> 4, bx = wb & 15;
  const float* src = (m == 0) ? qw : (m == 1) ? kw : (m == 2) ? vw
                   : (m == 3) ? gw : ow;
  const float scale = (m == 0) ? 0.1767766952966369f : 1.0f;
  const int d0 = (bx >> 2) * 64, o0 = (bx & 3) * 64;
  #pragma unroll
  for (int i = 0; i < 16; ++i) {
    const int idx = threadIdx.x + i * 256;
    tile[idx >> 6][idx & 63] = src[(size_t)(d0 + (idx >> 6)) * 256 + o0 + (idx & 63)];
  }
  __syncthreads();
  __hip_bfloat16* dst = Wt + (size_t)m * 65536;
  #pragma unroll
  for (int i = 0; i < 16; ++i) {
    const int idx = threadIdx.x + i * 256;
    const int orow = idx >> 6, dc = idx & 63;
    dst[(size_t)(o0 + orow) * 256 + d0 + dc] = __float2bfloat16(tile[dc][orow] * scale);
  }
}

// ---------------- Kernel 1: MFMA projections, reads raw f32 activations ----------------
__global__ __launch_bounds__(256) void proj_kernel(
    const float* __restrict__ qdata, const float* __restrict__ mdata,
    const __hip_bfloat16* __restrict__ Wt, const float* __restrict__ gating_b,
    __hip_bfloat16* __restrict__ Qw, __hip_bfloat16* __restrict__ Kw,
    __hip_bfloat16* __restrict__ Vt, __hip_bfloat16* __restrict__ G)
{
  const int wv = threadIdx.x >> 6, lane = threadIdx.x & 63;
  const int c = lane & 15, g = lane >> 4;
  const int task = blockIdx.x * 4 + wv;
  const int ctg = task & 3;
  const int mat = (task >> 2) & 1;
  const int r0g = (task >> 3) & 255;
  const int src = task >> 11;
  const int r0 = r0g * 16;
  const int b = r0 >> 10, pos0 = r0 & 1023;
  const f32x4 z = {0.f, 0.f, 0.f, 0.f};

  // load f32 activation row-fragment, convert to bf16 fragments in-register
  const float* A = (src ? mdata : qdata) + (size_t)(r0 + c) * 256;
  v8s af[8];
  #pragma unroll
  for (int ks = 0; ks < 8; ++ks) {
    const f32x4 a0 = *(const f32x4*)(A + ks * 32 + g * 8);
    const f32x4 a1 = *(const f32x4*)(A + ks * 32 + g * 8 + 4);
    __hip_bfloat16 t8[8];
    t8[0]=__float2bfloat16(a0.x); t8[1]=__float2bfloat16(a0.y);
    t8[2]=__float2bfloat16(a0.z); t8[3]=__float2bfloat16(a0.w);
    t8[4]=__float2bfloat16(a1.x); t8[5]=__float2bfloat16(a1.y);
    t8[6]=__float2bfloat16(a1.z); t8[7]=__float2bfloat16(a1.w);
    af[ks] = *(v8s*)t8;
  }

  const int widx = (src == 0) ? (mat ? 3 : 0) : (mat ? 2 : 1);
  const __hip_bfloat16* W = Wt + (size_t)widx * 65536;
  const bool swapped = (src == 1) && (mat == 1);   // value proj -> direct Vt layout

  f32x4 ac[4] = {z, z, z, z};
  #pragma unroll
  for (int ks = 0; ks < 8; ++ks) {
    #pragma unroll
    for (int j = 0; j < 4; ++j) {
      v8s wf = *(const v8s*)(W + (size_t)((ctg * 4 + j) * 16 + c) * 256 + ks * 32 + g * 8);
      ac[j] = swapped
        ? __builtin_amdgcn_mfma_f32_16x16x32_bf16(wf, af[ks], ac[j], 0, 0, 0)
        : __builtin_amdgcn_mfma_f32_16x16x32_bf16(af[ks], wf, ac[j], 0, 0, 0);
    }
  }

  if (src == 0 && mat == 0) {          // Qw
    #pragma unroll
    for (int j = 0; j < 4; ++j) {
      const int o = (ctg * 4 + j) * 16 + c, h = o >> 5, hd = o & 31;
      #pragma unroll
      for (int r = 0; r < 4; ++r)
        Qw[((size_t)(b * NH + h) * 1024 + pos0 + 4 * g + r) * 32 + hd] =
            __float2bfloat16(ac[j][r]);
    }
  } else if (src == 0) {               // G (gating logits, bf16)
    #pragma unroll
    for (int j = 0; j < 4; ++j) {
      const int o = (ctg * 4 + j) * 16 + c;
      const float gb = gating_b[o];
      #pragma unroll
      for (int r = 0; r < 4; ++r)
        G[(size_t)(r0 + 4 * g + r) * 256 + o] = __float2bfloat16(ac[j][r] + gb);
    }
  } else if (mat == 0) {               // Kw
    #pragma unroll
    for (int j = 0; j < 4; ++j) {
      const int o = (ctg * 4 + j) * 16 + c, h = o >> 5, hd = o & 31;
      #pragma unroll
      for (int r = 0; r < 4; ++r)
        Kw[((size_t)(b * NH + h) * 1024 + pos0 + 4 * g + r) * 32 + hd] =
            __float2bfloat16(ac[j][r]);
    }
  } else {                             // Vt (swapped): coalesced over pos
    #pragma unroll
    for (int j = 0; j < 4; ++j) {
      #pragma unroll
      for (int r = 0; r < 4; ++r) {
        const int o2 = (ctg * 4 + j) * 16 + 4 * g + r;
        Vt[((size_t)(b * NH + (o2 >> 5)) * 32 + (o2 & 31)) * 1024 + pos0 + c] =
            __float2bfloat16(ac[j][r]);
      }
    }
  }
}

// ---------------- Kernel 2: split-K flash attention, 2-wave (128-thread) blocks ----------------
// Residency probe: demand 16 blocks/CU (32 waves) via finer WG granularity.
// Same per-wave work/code as the 85.3us config; XCD-swizzled, SPLIT=4,
// plain logits stores, no online max, register ping-pong prefetch.
__global__ __launch_bounds__(128) void attn_kernel(
    const __hip_bfloat16* __restrict__ Qw, const __hip_bfloat16* __restrict__ Kw,
    const __hip_bfloat16* __restrict__ Vt,
    const float* __restrict__ bias, const float* __restrict__ nbb,
    float* __restrict__ out_logits,
    __hip_bfloat16* __restrict__ partO, float* __restrict__ partL)
{
  __shared__ __align__(16) __hip_bfloat16 sP[2][16][72];

  const int wv = threadIdx.x >> 6, lane = threadIdx.x & 63;
  const int c = lane & 15, g = lane >> 4;
  // XCD-aware decode: bid = slot*8 + xcd; 128 blocks per bh (sp x 32 qtg pairs)
  const int xcd   = blockIdx.x & 7;
  const int slot  = blockIdx.x >> 3;          // 0..511
  const int bh    = ((slot >> 7) << 3) | xcd; // 0..31
  const int inner = slot & 127;
  const int sp    = inner >> 5;               // 0..3
  const int qtg   = inner & 31;               // 0..31
  const int qt  = qtg * 2 + wv;               // 0..63
  const int b = bh >> 3, h = bh & 7;
  const int rem = bh * 64 + qt;
  const int q0 = qt * 16;
  const int kbase = sp * (NKS / SPLIT);
  const size_t bhs = (size_t)bh;

  const __hip_bfloat16* Kbase = Kw + bhs * NKS * NHD;
  const __hip_bfloat16* Vbase = Vt + bhs * NHD * NKS;
  const float* biasb = bias + (size_t)b * NKS;
  const float* nbbb  = nbb + ((size_t)h * NQ + q0) * NKS;

  const v8s qfrag = *(const v8s*)(Qw + (bhs * NQ + q0 + c) * NHD + g * 8);

  const f32x4 zacc = {0.f, 0.f, 0.f, 0.f};
  f32x4 O0 = zacc, O1 = zacc;
  float lsumL[4] = {0.f, 0.f, 0.f, 0.f};

  auto loadKV = [&](int k0, v8s* kf, v8s* vf) {
    kf[0] = *(const v8s*)(Kbase + (k0 +      c) * NHD + g * 8);
    kf[1] = *(const v8s*)(Kbase + (k0 + 16 + c) * NHD + g * 8);
    kf[2] = *(const v8s*)(Kbase + (k0 + 32 + c) * NHD + g * 8);
    kf[3] = *(const v8s*)(Kbase + (k0 + 48 + c) * NHD + g * 8);
    vf[0] = *(const v8s*)(Vbase + (     c) * NKS + k0 +      g * 8);
    vf[1] = *(const v8s*)(Vbase + (16 + c) * NKS + k0 +      g * 8);
    vf[2] = *(const v8s*)(Vbase + (     c) * NKS + k0 + 32 + g * 8);
    vf[3] = *(const v8s*)(Vbase + (16 + c) * NKS + k0 + 32 + g * 8);
  };
  auto loadBias = [&](int k0, float* bn) {
    #pragma unroll
    for (int t = 0; t < 4; ++t) {
      const float bvt = biasb[k0 + t * 16 + c];
      #pragma unroll
      for (int r = 0; r < 4; ++r)
        bn[t * 4 + r] = bvt + nbbb[(g * 4 + r) * NKS + k0 + t * 16 + c];
    }
  };

  auto compute = [&](int k0, const v8s* kf, const v8s* vf, const float* bn) {
    f32x4 S[4];
    #pragma unroll
    for (int t = 0; t < 4; ++t)
      S[t] = __builtin_amdgcn_mfma_f32_16x16x32_bf16(qfrag, kf[t], zacc, 0, 0, 0);

    #pragma unroll
    for (int r = 0; r < 4; ++r) {
      const int qrow = q0 + g * 4 + r;
      float* lp = out_logits + (bhs * NQ + qrow) * (size_t)NKS + k0 + c;
      float psum = 0.f;
      #pragma unroll
      for (int t = 0; t < 4; ++t) {
        lp[t * 16] = S[t][r];
        const float p = __expf(S[t][r] + bn[t * 4 + r]);
        psum += p;
        sP[wv][g * 4 + r][t * 16 + c] = __float2bfloat16(p);
      }
      lsumL[r] += psum;
    }

    const v8s pa0 = *(const v8s*)&sP[wv][c][g * 8];
    const v8s pa1 = *(const v8s*)&sP[wv][c][32 + g * 8];
    O0 = __builtin_amdgcn_mfma_f32_16x16x32_bf16(pa0, vf[0], O0, 0, 0, 0);
    O0 = __builtin_amdgcn_mfma_f32_16x16x32_bf16(pa1, vf[2], O0, 0, 0, 0);
    O1 = __builtin_amdgcn_mfma_f32_16x16x32_bf16(pa0, vf[1], O1, 0, 0, 0);
    O1 = __builtin_amdgcn_mfma_f32_16x16x32_bf16(pa1, vf[3], O1, 0, 0, 0);
  };

  v8s kfA[4], vfA[4], kfB[4], vfB[4];
  float bnA[16], bnB[16];

  loadKV(kbase, kfA, vfA);
  loadBias(kbase, bnA);
  #pragma unroll 1
  for (int kt = 0; kt < NKS / SPLIT / 64; kt += 2) {
    loadKV(kbase + (kt + 1) * 64, kfB, vfB);
    loadBias(kbase + (kt + 1) * 64, bnB);
    compute(kbase + kt * 64, kfA, vfA, bnA);
    if (kt + 2 < NKS / SPLIT / 64) {
      loadKV(kbase + (kt + 2) * 64, kfA, vfA);
      loadBias(kbase + (kt + 2) * 64, bnA);
    }
    compute(kbase + (kt + 1) * 64, kfB, vfB, bnB);
  }

  // deferred cross-lane lsum reduce + partial write (O as bf16)
  #pragma unroll
  for (int r = 0; r < 4; ++r) {
    float rs = lsumL[r];
    rs += __shfl_xor(rs, 1);
    rs += __shfl_xor(rs, 2);
    rs += __shfl_xor(rs, 4);
    rs += __shfl_xor(rs, 8);
    const int row = 4 * g + r;
    const size_t pb = ((size_t)(rem * SPLIT + sp) * 16 + row) * 32;
    partO[pb + c]      = __float2bfloat16(O0[r]);
    partO[pb + 16 + c] = __float2bfloat16(O1[r]);
    if (c == 0) partL[(size_t)(rem * SPLIT + sp) * 16 + row] = rs;
  }
}

// ---------------- Kernel 3: fused merge + gate + MFMA output projection ----------------
__global__ __launch_bounds__(256) void outproj_kernel(
    const __hip_bfloat16* __restrict__ partO, const float* __restrict__ partL,
    const __hip_bfloat16* __restrict__ G, const __hip_bfloat16* __restrict__ WtO,
    const float* __restrict__ output_b, float* __restrict__ out)
{
  __shared__ __align__(16) __hip_bfloat16 sRows[16][264];
  const int t = threadIdx.x;
  const int wv = t >> 6, lane = t & 63;
  const int c = lane & 15, g = lane >> 4;
  const int r0 = blockIdx.x * 16;
  const int b = r0 >> 10, qt = (r0 & 1023) >> 4;
  const int h = t >> 5, hd = t & 31;
  const int rem = (b * NH + h) * 64 + qt;

  #pragma unroll 4
  for (int row = 0; row < 16; ++row) {
    float o = 0.f, l = 0.f;
    #pragma unroll
    for (int sp = 0; sp < SPLIT; ++sp) {
      const size_t base = (size_t)(rem * SPLIT + sp) * 16 + row;
      o += __bfloat162float(partO[base * 32 + hd]);
      l += partL[base];
    }
    const float gl = __bfloat162float(G[(size_t)(r0 + row) * 256 + t]);
    sRows[row][t] = __float2bfloat16((o / l) * (1.f / (1.f + __expf(-gl))));
  }
  __syncthreads();

  const f32x4 z = {0.f, 0.f, 0.f, 0.f};
  f32x4 ac[4] = {z, z, z, z};
  #pragma unroll
  for (int ks = 0; ks < 8; ++ks) {
    const v8s af = *(const v8s*)&sRows[c][ks * 32 + g * 8];
    #pragma unroll
    for (int j = 0; j < 4; ++j) {
      const v8s wf = *(const v8s*)(WtO + (size_t)((wv * 4 + j) * 16 + c) * 256 + ks * 32 + g * 8);
      ac[j] = __builtin_amdgcn_mfma_f32_16x16x32_bf16(af, wf, ac[j], 0, 0, 0);
    }
  }
  #pragma unroll
  for (int j = 0; j < 4; ++j) {
    const int o = (wv * 4 + j) * 16 + c;
    const float ob = output_b[o];
    #pragma unroll
    for (int r = 0; r < 4; ++r)
      out[(size_t)(r0 + 4 * g + r) * 256 + o] = ac[j][r] + ob;
  }
}

extern "C" void kernel_launch(void* const* d_in, const int* in_sizes, int n_in,
                              void* d_out, int out_size, void* d_ws, size_t ws_size,
                              hipStream_t stream) {
  const float* q_data   = (const float*)d_in[0];
  const float* m_data   = (const float*)d_in[1];
  const float* bias     = (const float*)d_in[2];
  const float* nbb      = (const float*)d_in[3];
  const float* query_w  = (const float*)d_in[4];
  const float* key_w    = (const float*)d_in[5];
  const float* value_w  = (const float*)d_in[6];
  const float* gating_w = (const float*)d_in[7];
  const float* gating_b = (const float*)d_in[8];
  const float* output_w = (const float*)d_in[9];
  const float* output_b = (const float*)d_in[10];

  float* out        = (float*)d_out;
  float* out_logits = out + (size_t)NB * NQ * NOUT;

  char* ws = (char*)d_ws;
  const size_t MB = 1u << 20;
  __hip_bfloat16* Qw  = (__hip_bfloat16*)(ws);              // 2MB @0
  __hip_bfloat16* Kw  = (__hip_bfloat16*)(ws + 2 * MB);     // 2MB @2
  __hip_bfloat16* Vt  = (__hip_bfloat16*)(ws + 4 * MB);     // 2MB @4
  __hip_bfloat16* G   = (__hip_bfloat16*)(ws + 6 * MB);     // 2MB @6 (bf16)
  __hip_bfloat16* partO = (__hip_bfloat16*)(ws + 10 * MB);  // 8MB @10..18
  float*          partL = (float*)(ws + 19 * MB);           // 0.5MB @19
  __hip_bfloat16* Wt  = (__hip_bfloat16*)(ws + 20 * MB);    // 640KB @20

  prep_w<<<80, 256, 0, stream>>>(query_w, key_w, value_w, gating_w, output_w, Wt);
  proj_kernel<<<1024, 256, 0, stream>>>(q_data, m_data, Wt, gating_b, Qw, Kw, Vt, G);
  attn_kernel<<<4096, 128, 0, stream>>>(Qw, Kw, Vt, bias, nbb, out_logits, partO, partL);
  outproj_kernel<<<256, 256, 0, stream>>>(partO, partL, G, Wt + (size_t)4 * 65536,
                                          output_b, out);
}

// Round 17
// 85.574 us; speedup vs baseline: 1.0048x; 1.0048x over previous
//
#include <hip/hip_runtime.h>
#include <hip/hip_bf16.h>

#define NB 4
#define NQ 1024
#define NKS 1024
#define ND 256
#define NH 8
#define NHD 32
#define NOUT 256
#define SPLIT 4

typedef __attribute__((ext_vector_type(8))) short v8s;
typedef __attribute__((ext_vector_type(4))) short v4s;
typedef __attribute__((ext_vector_type(4))) float f32x4;

// ---------------- prep (fused): activations->bf16  +  weight transpose ----------------
// blocks [0,1024): data; blocks [1024,1104): weights (5 matrices x 16 tiles)
__global__ __launch_bounds__(256) void prep_all(
    const float* __restrict__ qd, const float* __restrict__ md,
    const float* __restrict__ qw, const float* __restrict__ kw,
    const float* __restrict__ vw, const float* __restrict__ gw,
    const float* __restrict__ ow,
    __hip_bfloat16* __restrict__ Abf, __hip_bfloat16* __restrict__ Wt)
{
  if (blockIdx.x < 1024) {
    const int gid = blockIdx.x * 256 + threadIdx.x;     // 0..262143
    const float* src = (gid < 131072) ? qd : md;
    const size_t off = (size_t)(gid & 131071) * 8;
    const float4 a = ((const float4*)(src + off))[0];
    const float4 c = ((const float4*)(src + off))[1];
    __hip_bfloat16 t8[8];
    t8[0]=__float2bfloat16(a.x); t8[1]=__float2bfloat16(a.y);
    t8[2]=__float2bfloat16(a.z); t8[3]=__float2bfloat16(a.w);
    t8[4]=__float2bfloat16(c.x); t8[5]=__float2bfloat16(c.y);
    t8[6]=__float2bfloat16(c.z); t8[7]=__float2bfloat16(c.w);
    *(v8s*)(Abf + (size_t)gid * 8) = *(v8s*)t8;
    return;
  }
  __shared__ float tile[64][65];
  const int wb = blockIdx.x - 1024;          // 0..79
  const int m = wb >> 4, bx = wb & 15;
  const float* src = (m == 0) ? qw : (m == 1) ? kw : (m == 2) ? vw
                   : (m == 3) ? gw : ow;
  const float scale = (m == 0) ? 0.1767766952966369f : 1.0f;
  const int d0 = (bx >> 2) * 64, o0 = (bx & 3) * 64;
  #pragma unroll
  for (int i = 0; i < 16; ++i) {
    const int idx = threadIdx.x + i * 256;
    tile[idx >> 6][idx & 63] = src[(size_t)(d0 + (idx >> 6)) * 256 + o0 + (idx & 63)];
  }
  __syncthreads();
  __hip_bfloat16* dst = Wt + (size_t)m * 65536;
  #pragma unroll
  for (int i = 0; i < 16; ++i) {
    const int idx = threadIdx.x + i * 256;
    const int orow = idx >> 6, dc = idx & 63;
    dst[(size_t)(o0 + orow) * 256 + d0 + dc] = __float2bfloat16(tile[dc][orow] * scale);
  }
}

// ---------------- Kernel 1: MFMA projections, 4 waves/block ----------------
__global__ __launch_bounds__(256) void proj_kernel(
    const __hip_bfloat16* __restrict__ Abf, const __hip_bfloat16* __restrict__ Wt,
    const float* __restrict__ gating_b,
    __hip_bfloat16* __restrict__ Qw, __hip_bfloat16* __restrict__ Kw,
    __hip_bfloat16* __restrict__ Vt, __hip_bfloat16* __restrict__ G)
{
  const int wv = threadIdx.x >> 6, lane = threadIdx.x & 63;
  const int c = lane & 15, g = lane >> 4;
  const int task = blockIdx.x * 4 + wv;
  const int ctg = task & 3;
  const int mat = (task >> 2) & 1;
  const int r0g = (task >> 3) & 255;
  const int src = task >> 11;
  const int r0 = r0g * 16;
  const int b = r0 >> 10, pos0 = r0 & 1023;
  const f32x4 z = {0.f, 0.f, 0.f, 0.f};

  const __hip_bfloat16* A = Abf + ((size_t)src * 4096 + r0) * 256;
  v8s af[8];
  #pragma unroll
  for (int ks = 0; ks < 8; ++ks)
    af[ks] = *(const v8s*)(A + c * 256 + ks * 32 + g * 8);

  const int widx = (src == 0) ? (mat ? 3 : 0) : (mat ? 2 : 1);
  const __hip_bfloat16* W = Wt + (size_t)widx * 65536;
  const bool swapped = (src == 1) && (mat == 1);   // value proj -> direct Vt layout

  f32x4 ac[4] = {z, z, z, z};
  #pragma unroll
  for (int ks = 0; ks < 8; ++ks) {
    #pragma unroll
    for (int j = 0; j < 4; ++j) {
      v8s wf = *(const v8s*)(W + (size_t)((ctg * 4 + j) * 16 + c) * 256 + ks * 32 + g * 8);
      ac[j] = swapped
        ? __builtin_amdgcn_mfma_f32_16x16x32_bf16(wf, af[ks], ac[j], 0, 0, 0)
        : __builtin_amdgcn_mfma_f32_16x16x32_bf16(af[ks], wf, ac[j], 0, 0, 0);
    }
  }

  if (src == 0 && mat == 0) {          // Qw
    #pragma unroll
    for (int j = 0; j < 4; ++j) {
      const int o = (ctg * 4 + j) * 16 + c, h = o >> 5, hd = o & 31;
      #pragma unroll
      for (int r = 0; r < 4; ++r)
        Qw[((size_t)(b * NH + h) * 1024 + pos0 + 4 * g + r) * 32 + hd] =
            __float2bfloat16(ac[j][r]);
    }
  } else if (src == 0) {               // G (gating logits, bf16)
    #pragma unroll
    for (int j = 0; j < 4; ++j) {
      const int o = (ctg * 4 + j) * 16 + c;
      const float gb = gating_b[o];
      #pragma unroll
      for (int r = 0; r < 4; ++r)
        G[(size_t)(r0 + 4 * g + r) * 256 + o] = __float2bfloat16(ac[j][r] + gb);
    }
  } else if (mat == 0) {               // Kw
    #pragma unroll
    for (int j = 0; j < 4; ++j) {
      const int o = (ctg * 4 + j) * 16 + c, h = o >> 5, hd = o & 31;
      #pragma unroll
      for (int r = 0; r < 4; ++r)
        Kw[((size_t)(b * NH + h) * 1024 + pos0 + 4 * g + r) * 32 + hd] =
            __float2bfloat16(ac[j][r]);
    }
  } else {                             // Vt (swapped): coalesced over pos
    #pragma unroll
    for (int j = 0; j < 4; ++j) {
      #pragma unroll
      for (int r = 0; r < 4; ++r) {
        const int o2 = (ctg * 4 + j) * 16 + 4 * g + r;
        Vt[((size_t)(b * NH + (o2 >> 5)) * 32 + (o2 & 31)) * 1024 + pos0 + c] =
            __float2bfloat16(ac[j][r]);
      }
    }
  }
}

// ---------------- Kernel 2: split-K flash attention, SPLIT=4, XCD-swizzled ----------------
// Measured-best configuration (84.7us total): default occupancy (~68 VGPR),
// register ping-pong prefetch, plain logits stores, no online max.
__global__ __launch_bounds__(256) void attn_kernel(
    const __hip_bfloat16* __restrict__ Qw, const __hip_bfloat16* __restrict__ Kw,
    const __hip_bfloat16* __restrict__ Vt,
    const float* __restrict__ bias, const float* __restrict__ nbb,
    float* __restrict__ out_logits,
    __hip_bfloat16* __restrict__ partO, float* __restrict__ partL)
{
  __shared__ __align__(16) __hip_bfloat16 sP[4][16][72];

  const int wv = threadIdx.x >> 6, lane = threadIdx.x & 63;
  const int c = lane & 15, g = lane >> 4;
  // XCD-aware decode: bid = slot*8 + xcd; bh = (slot>>6)*8 + xcd
  const int xcd   = blockIdx.x & 7;
  const int slot  = blockIdx.x >> 3;          // 0..255
  const int bh    = ((slot >> 6) << 3) | xcd; // 0..31
  const int inner = slot & 63;
  const int sp    = inner >> 4;               // 0..3
  const int qtg   = inner & 15;
  const int qt  = qtg * 4 + wv;               // 0..63
  const int b = bh >> 3, h = bh & 7;
  const int rem = bh * 64 + qt;
  const int q0 = qt * 16;
  const int kbase = sp * (NKS / SPLIT);
  const size_t bhs = (size_t)bh;

  const __hip_bfloat16* Kbase = Kw + bhs * NKS * NHD;
  const __hip_bfloat16* Vbase = Vt + bhs * NHD * NKS;
  const float* biasb = bias + (size_t)b * NKS;
  const float* nbbb  = nbb + ((size_t)h * NQ + q0) * NKS;

  const v8s qfrag = *(const v8s*)(Qw + (bhs * NQ + q0 + c) * NHD + g * 8);

  const f32x4 zacc = {0.f, 0.f, 0.f, 0.f};
  f32x4 O0 = zacc, O1 = zacc;
  float lsumL[4] = {0.f, 0.f, 0.f, 0.f};

  auto loadKV = [&](int k0, v8s* kf, v8s* vf) {
    kf[0] = *(const v8s*)(Kbase + (k0 +      c) * NHD + g * 8);
    kf[1] = *(const v8s*)(Kbase + (k0 + 16 + c) * NHD + g * 8);
    kf[2] = *(const v8s*)(Kbase + (k0 + 32 + c) * NHD + g * 8);
    kf[3] = *(const v8s*)(Kbase + (k0 + 48 + c) * NHD + g * 8);
    vf[0] = *(const v8s*)(Vbase + (     c) * NKS + k0 +      g * 8);
    vf[1] = *(const v8s*)(Vbase + (16 + c) * NKS + k0 +      g * 8);
    vf[2] = *(const v8s*)(Vbase + (     c) * NKS + k0 + 32 + g * 8);
    vf[3] = *(const v8s*)(Vbase + (16 + c) * NKS + k0 + 32 + g * 8);
  };
  // bn[t*4+r] = bias[col] + nbb[row][col]  (adds done at load time, off hot path)
  auto loadBias = [&](int k0, float* bn) {
    #pragma unroll
    for (int t = 0; t < 4; ++t) {
      const float bvt = biasb[k0 + t * 16 + c];
      #pragma unroll
      for (int r = 0; r < 4; ++r)
        bn[t * 4 + r] = bvt + nbbb[(g * 4 + r) * NKS + k0 + t * 16 + c];
    }
  };

  auto compute = [&](int k0, const v8s* kf, const v8s* vf, const float* bn) {
    f32x4 S[4];
    #pragma unroll
    for (int t = 0; t < 4; ++t)
      S[t] = __builtin_amdgcn_mfma_f32_16x16x32_bf16(qfrag, kf[t], zacc, 0, 0, 0);

    #pragma unroll
    for (int r = 0; r < 4; ++r) {
      const int qrow = q0 + g * 4 + r;
      float* lp = out_logits + (bhs * NQ + qrow) * (size_t)NKS + k0 + c;
      float psum = 0.f;
      #pragma unroll
      for (int t = 0; t < 4; ++t) {
        lp[t * 16] = S[t][r];
        const float p = __expf(S[t][r] + bn[t * 4 + r]);
        psum += p;
        sP[wv][g * 4 + r][t * 16 + c] = __float2bfloat16(p);
      }
      lsumL[r] += psum;
    }

    const v8s pa0 = *(const v8s*)&sP[wv][c][g * 8];
    const v8s pa1 = *(const v8s*)&sP[wv][c][32 + g * 8];
    O0 = __builtin_amdgcn_mfma_f32_16x16x32_bf16(pa0, vf[0], O0, 0, 0, 0);
    O0 = __builtin_amdgcn_mfma_f32_16x16x32_bf16(pa1, vf[2], O0, 0, 0, 0);
    O1 = __builtin_amdgcn_mfma_f32_16x16x32_bf16(pa0, vf[1], O1, 0, 0, 0);
    O1 = __builtin_amdgcn_mfma_f32_16x16x32_bf16(pa1, vf[3], O1, 0, 0, 0);
  };

  v8s kfA[4], vfA[4], kfB[4], vfB[4];
  float bnA[16], bnB[16];

  loadKV(kbase, kfA, vfA);
  loadBias(kbase, bnA);
  #pragma unroll 1
  for (int kt = 0; kt < NKS / SPLIT / 64; kt += 2) {
    loadKV(kbase + (kt + 1) * 64, kfB, vfB);
    loadBias(kbase + (kt + 1) * 64, bnB);
    compute(kbase + kt * 64, kfA, vfA, bnA);
    if (kt + 2 < NKS / SPLIT / 64) {
      loadKV(kbase + (kt + 2) * 64, kfA, vfA);
      loadBias(kbase + (kt + 2) * 64, bnA);
    }
    compute(kbase + (kt + 1) * 64, kfB, vfB, bnB);
  }

  // deferred cross-lane lsum reduce + partial write (O as bf16)
  #pragma unroll
  for (int r = 0; r < 4; ++r) {
    float rs = lsumL[r];
    rs += __shfl_xor(rs, 1);
    rs += __shfl_xor(rs, 2);
    rs += __shfl_xor(rs, 4);
    rs += __shfl_xor(rs, 8);
    const int row = 4 * g + r;
    const size_t pb = ((size_t)(rem * SPLIT + sp) * 16 + row) * 32;
    partO[pb + c]      = __float2bfloat16(O0[r]);
    partO[pb + 16 + c] = __float2bfloat16(O1[r]);
    if (c == 0) partL[(size_t)(rem * SPLIT + sp) * 16 + row] = rs;
  }
}

// ---------------- Kernel 3: fused merge + gate + MFMA output projection ----------------
// 512 blocks: bx -> (16-row group, column half); 2 blocks/CU for latency hiding.
__global__ __launch_bounds__(256) void outproj_kernel(
    const __hip_bfloat16* __restrict__ partO, const float* __restrict__ partL,
    const __hip_bfloat16* __restrict__ G, const __hip_bfloat16* __restrict__ WtO,
    const float* __restrict__ output_b, float* __restrict__ out)
{
  __shared__ __align__(16) __hip_bfloat16 sRows[16][264];
  const int t = threadIdx.x;
  const int wv = t >> 6, lane = t & 63;
  const int c = lane & 15, g = lane >> 4;
  const int r0 = (blockIdx.x >> 1) * 16;
  const int colh = blockIdx.x & 1;
  const int b = r0 >> 10, qt = (r0 & 1023) >> 4;
  const int h = t >> 5, hd = t & 31;
  const int rem = (b * NH + h) * 64 + qt;

  #pragma unroll 4
  for (int row = 0; row < 16; ++row) {
    float o = 0.f, l = 0.f;
    #pragma unroll
    for (int sp = 0; sp < SPLIT; ++sp) {
      const size_t base = (size_t)(rem * SPLIT + sp) * 16 + row;
      o += __bfloat162float(partO[base * 32 + hd]);
      l += partL[base];
    }
    const float gl = __bfloat162float(G[(size_t)(r0 + row) * 256 + t]);
    sRows[row][t] = __float2bfloat16((o / l) * (1.f / (1.f + __expf(-gl))));
  }
  __syncthreads();

  const f32x4 z = {0.f, 0.f, 0.f, 0.f};
  f32x4 ac[2] = {z, z};
  #pragma unroll
  for (int ks = 0; ks < 8; ++ks) {
    const v8s af = *(const v8s*)&sRows[c][ks * 32 + g * 8];
    #pragma unroll
    for (int j = 0; j < 2; ++j) {
      const int o = colh * 128 + (wv * 2 + j) * 16 + c;
      const v8s wf = *(const v8s*)(WtO + (size_t)o * 256 + ks * 32 + g * 8);
      ac[j] = __builtin_amdgcn_mfma_f32_16x16x32_bf16(af, wf, ac[j], 0, 0, 0);
    }
  }
  #pragma unroll
  for (int j = 0; j < 2; ++j) {
    const int o = colh * 128 + (wv * 2 + j) * 16 + c;
    const float ob = output_b[o];
    #pragma unroll
    for (int r = 0; r < 4; ++r)
      out[(size_t)(r0 + 4 * g + r) * 256 + o] = ac[j][r] + ob;
  }
}

extern "C" void kernel_launch(void* const* d_in, const int* in_sizes, int n_in,
                              void* d_out, int out_size, void* d_ws, size_t ws_size,
                              hipStream_t stream) {
  const float* q_data   = (const float*)d_in[0];
  const float* m_data   = (const float*)d_in[1];
  const float* bias     = (const float*)d_in[2];
  const float* nbb      = (const float*)d_in[3];
  const float* query_w  = (const float*)d_in[4];
  const float* key_w    = (const float*)d_in[5];
  const float* value_w  = (const float*)d_in[6];
  const float* gating_w = (const float*)d_in[7];
  const float* gating_b = (const float*)d_in[8];
  const float* output_w = (const float*)d_in[9];
  const float* output_b = (const float*)d_in[10];

  float* out        = (float*)d_out;
  float* out_logits = out + (size_t)NB * NQ * NOUT;

  char* ws = (char*)d_ws;
  const size_t MB = 1u << 20;
  __hip_bfloat16* Qw  = (__hip_bfloat16*)(ws);              // 2MB @0
  __hip_bfloat16* Kw  = (__hip_bfloat16*)(ws + 2 * MB);     // 2MB @2
  __hip_bfloat16* Vt  = (__hip_bfloat16*)(ws + 4 * MB);     // 2MB @4
  __hip_bfloat16* G   = (__hip_bfloat16*)(ws + 6 * MB);     // 2MB @6 (bf16)
  __hip_bfloat16* Abf = (__hip_bfloat16*)(ws + 10 * MB);    // 4MB @10 (dead after proj)
  // partO aliases Abf (stream order serializes proj -> attn)
  __hip_bfloat16* partO = (__hip_bfloat16*)(ws + 10 * MB);  // 8MB @10..18
  float*          partL = (float*)(ws + 19 * MB);           // 0.5MB @19
  __hip_bfloat16* Wt  = (__hip_bfloat16*)(ws + 20 * MB);    // 640KB @20 (read by proj AND outproj)

  prep_all<<<1104, 256, 0, stream>>>(q_data, m_data, query_w, key_w, value_w,
                                     gating_w, output_w, Abf, Wt);
  proj_kernel<<<1024, 256, 0, stream>>>(Abf, Wt, gating_b, Qw, Kw, Vt, G);
  attn_kernel<<<2048, 256, 0, stream>>>(Qw, Kw, Vt, bias, nbb, out_logits, partO, partL);
  outproj_kernel<<<512, 256, 0, stream>>>(partO, partL, G, Wt + (size_t)4 * 65536,
                                          output_b, out);
}

// Round 18
// 77.821 us; speedup vs baseline: 1.1049x; 1.0996x over previous
//
#include <hip/hip_runtime.h>
#include <hip/hip_bf16.h>

#define NB 4
#define NQ 1024
#define NKS 1024
#define ND 256
#define NH 8
#define NHD 32
#define NOUT 256

typedef __attribute__((ext_vector_type(8))) short v8s;
typedef __attribute__((ext_vector_type(4))) short v4s;
typedef __attribute__((ext_vector_type(4))) float f32x4;

// ---------------- prep (fused): activations->bf16  +  weight transpose ----------------
// blocks [0,1024): data; blocks [1024,1104): weights (5 matrices x 16 tiles)
__global__ __launch_bounds__(256) void prep_all(
    const float* __restrict__ qd, const float* __restrict__ md,
    const float* __restrict__ qw, const float* __restrict__ kw,
    const float* __restrict__ vw, const float* __restrict__ gw,
    const float* __restrict__ ow,
    __hip_bfloat16* __restrict__ Abf, __hip_bfloat16* __restrict__ Wt)
{
  if (blockIdx.x < 1024) {
    const int gid = blockIdx.x * 256 + threadIdx.x;     // 0..262143
    const float* src = (gid < 131072) ? qd : md;
    const size_t off = (size_t)(gid & 131071) * 8;
    const float4 a = ((const float4*)(src + off))[0];
    const float4 c = ((const float4*)(src + off))[1];
    __hip_bfloat16 t8[8];
    t8[0]=__float2bfloat16(a.x); t8[1]=__float2bfloat16(a.y);
    t8[2]=__float2bfloat16(a.z); t8[3]=__float2bfloat16(a.w);
    t8[4]=__float2bfloat16(c.x); t8[5]=__float2bfloat16(c.y);
    t8[6]=__float2bfloat16(c.z); t8[7]=__float2bfloat16(c.w);
    *(v8s*)(Abf + (size_t)gid * 8) = *(v8s*)t8;
    return;
  }
  __shared__ float tile[64][65];
  const int wb = blockIdx.x - 1024;          // 0..79
  const int m = wb >> 4, bx = wb & 15;
  const float* src = (m == 0) ? qw : (m == 1) ? kw : (m == 2) ? vw
                   : (m == 3) ? gw : ow;
  const float scale = (m == 0) ? 0.1767766952966369f : 1.0f;
  const int d0 = (bx >> 2) * 64, o0 = (bx & 3) * 64;
  #pragma unroll
  for (int i = 0; i < 16; ++i) {
    const int idx = threadIdx.x + i * 256;
    tile[idx >> 6][idx & 63] = src[(size_t)(d0 + (idx >> 6)) * 256 + o0 + (idx & 63)];
  }
  __syncthreads();
  __hip_bfloat16* dst = Wt + (size_t)m * 65536;
  #pragma unroll
  for (int i = 0; i < 16; ++i) {
    const int idx = threadIdx.x + i * 256;
    const int orow = idx >> 6, dc = idx & 63;
    dst[(size_t)(o0 + orow) * 256 + d0 + dc] = __float2bfloat16(tile[dc][orow] * scale);
  }
}

// ---------------- Kernel 1: MFMA projections, 4 waves/block ----------------
__global__ __launch_bounds__(256) void proj_kernel(
    const __hip_bfloat16* __restrict__ Abf, const __hip_bfloat16* __restrict__ Wt,
    const float* __restrict__ gating_b,
    __hip_bfloat16* __restrict__ Qw, __hip_bfloat16* __restrict__ Kw,
    __hip_bfloat16* __restrict__ Vt, __hip_bfloat16* __restrict__ G)
{
  const int wv = threadIdx.x >> 6, lane = threadIdx.x & 63;
  const int c = lane & 15, g = lane >> 4;
  const int task = blockIdx.x * 4 + wv;
  const int ctg = task & 3;
  const int mat = (task >> 2) & 1;
  const int r0g = (task >> 3) & 255;
  const int src = task >> 11;
  const int r0 = r0g * 16;
  const int b = r0 >> 10, pos0 = r0 & 1023;
  const f32x4 z = {0.f, 0.f, 0.f, 0.f};

  const __hip_bfloat16* A = Abf + ((size_t)src * 4096 + r0) * 256;
  v8s af[8];
  #pragma unroll
  for (int ks = 0; ks < 8; ++ks)
    af[ks] = *(const v8s*)(A + c * 256 + ks * 32 + g * 8);

  const int widx = (src == 0) ? (mat ? 3 : 0) : (mat ? 2 : 1);
  const __hip_bfloat16* W = Wt + (size_t)widx * 65536;
  const bool swapped = (src == 1) && (mat == 1);   // value proj -> direct Vt layout

  f32x4 ac[4] = {z, z, z, z};
  #pragma unroll
  for (int ks = 0; ks < 8; ++ks) {
    #pragma unroll
    for (int j = 0; j < 4; ++j) {
      v8s wf = *(const v8s*)(W + (size_t)((ctg * 4 + j) * 16 + c) * 256 + ks * 32 + g * 8);
      ac[j] = swapped
        ? __builtin_amdgcn_mfma_f32_16x16x32_bf16(wf, af[ks], ac[j], 0, 0, 0)
        : __builtin_amdgcn_mfma_f32_16x16x32_bf16(af[ks], wf, ac[j], 0, 0, 0);
    }
  }

  if (src == 0 && mat == 0) {          // Qw
    #pragma unroll
    for (int j = 0; j < 4; ++j) {
      const int o = (ctg * 4 + j) * 16 + c, h = o >> 5, hd = o & 31;
      #pragma unroll
      for (int r = 0; r < 4; ++r)
        Qw[((size_t)(b * NH + h) * 1024 + pos0 + 4 * g + r) * 32 + hd] =
            __float2bfloat16(ac[j][r]);
    }
  } else if (src == 0) {               // G (gating logits, bf16)
    #pragma unroll
    for (int j = 0; j < 4; ++j) {
      const int o = (ctg * 4 + j) * 16 + c;
      const float gb = gating_b[o];
      #pragma unroll
      for (int r = 0; r < 4; ++r)
        G[(size_t)(r0 + 4 * g + r) * 256 + o] = __float2bfloat16(ac[j][r] + gb);
    }
  } else if (mat == 0) {               // Kw
    #pragma unroll
    for (int j = 0; j < 4; ++j) {
      const int o = (ctg * 4 + j) * 16 + c, h = o >> 5, hd = o & 31;
      #pragma unroll
      for (int r = 0; r < 4; ++r)
        Kw[((size_t)(b * NH + h) * 1024 + pos0 + 4 * g + r) * 32 + hd] =
            __float2bfloat16(ac[j][r]);
    }
  } else {                             // Vt (swapped): coalesced over pos
    #pragma unroll
    for (int j = 0; j < 4; ++j) {
      #pragma unroll
      for (int r = 0; r < 4; ++r) {
        const int o2 = (ctg * 4 + j) * 16 + 4 * g + r;
        Vt[((size_t)(b * NH + (o2 >> 5)) * 32 + (o2 & 31)) * 1024 + pos0 + c] =
            __float2bfloat16(ac[j][r]);
      }
    }
  }
}

// ---------------- Kernel 2: flash attention, SPLIT=1, gate fused ----------------
// 512 blocks (XCD-swizzled: 4 bh per XCD, K/V L2-pinned), 4 waves/block,
// full K=1024 per wave, no partials: normalize + sigmoid-gate in-kernel,
// write final gated rows to WA (bf16). No online max (logits bounded).
__global__ __launch_bounds__(256) void attn_kernel(
    const __hip_bfloat16* __restrict__ Qw, const __hip_bfloat16* __restrict__ Kw,
    const __hip_bfloat16* __restrict__ Vt,
    const float* __restrict__ bias, const float* __restrict__ nbb,
    const __hip_bfloat16* __restrict__ G,
    float* __restrict__ out_logits, __hip_bfloat16* __restrict__ WA)
{
  __shared__ __align__(16) __hip_bfloat16 sP[4][16][72];

  const int wv = threadIdx.x >> 6, lane = threadIdx.x & 63;
  const int c = lane & 15, g = lane >> 4;
  // XCD-aware decode: bid = slot*8 + xcd; bh = ((slot>>4)<<3) | xcd
  const int xcd   = blockIdx.x & 7;
  const int slot  = blockIdx.x >> 3;          // 0..63
  const int bh    = ((slot >> 4) << 3) | xcd; // 0..31
  const int qtg   = slot & 15;
  const int qt  = qtg * 4 + wv;               // 0..63
  const int b = bh >> 3, h = bh & 7;
  const int q0 = qt * 16;
  const size_t bhs = (size_t)bh;

  const __hip_bfloat16* Kbase = Kw + bhs * NKS * NHD;
  const __hip_bfloat16* Vbase = Vt + bhs * NHD * NKS;
  const float* biasb = bias + (size_t)b * NKS;
  const float* nbbb  = nbb + ((size_t)h * NQ + q0) * NKS;

  const v8s qfrag = *(const v8s*)(Qw + (bhs * NQ + q0 + c) * NHD + g * 8);

  const f32x4 zacc = {0.f, 0.f, 0.f, 0.f};
  f32x4 O0 = zacc, O1 = zacc;
  float lsumL[4] = {0.f, 0.f, 0.f, 0.f};

  auto loadKV = [&](int k0, v8s* kf, v8s* vf) {
    kf[0] = *(const v8s*)(Kbase + (k0 +      c) * NHD + g * 8);
    kf[1] = *(const v8s*)(Kbase + (k0 + 16 + c) * NHD + g * 8);
    kf[2] = *(const v8s*)(Kbase + (k0 + 32 + c) * NHD + g * 8);
    kf[3] = *(const v8s*)(Kbase + (k0 + 48 + c) * NHD + g * 8);
    vf[0] = *(const v8s*)(Vbase + (     c) * NKS + k0 +      g * 8);
    vf[1] = *(const v8s*)(Vbase + (16 + c) * NKS + k0 +      g * 8);
    vf[2] = *(const v8s*)(Vbase + (     c) * NKS + k0 + 32 + g * 8);
    vf[3] = *(const v8s*)(Vbase + (16 + c) * NKS + k0 + 32 + g * 8);
  };
  // bn[t*4+r] = bias[col] + nbb[row][col]  (adds done at load time, off hot path)
  auto loadBias = [&](int k0, float* bn) {
    #pragma unroll
    for (int t = 0; t < 4; ++t) {
      const float bvt = biasb[k0 + t * 16 + c];
      #pragma unroll
      for (int r = 0; r < 4; ++r)
        bn[t * 4 + r] = bvt + nbbb[(g * 4 + r) * NKS + k0 + t * 16 + c];
    }
  };

  auto compute = [&](int k0, const v8s* kf, const v8s* vf, const float* bn) {
    f32x4 S[4];
    #pragma unroll
    for (int t = 0; t < 4; ++t)
      S[t] = __builtin_amdgcn_mfma_f32_16x16x32_bf16(qfrag, kf[t], zacc, 0, 0, 0);

    #pragma unroll
    for (int r = 0; r < 4; ++r) {
      const int qrow = q0 + g * 4 + r;
      float* lp = out_logits + (bhs * NQ + qrow) * (size_t)NKS + k0 + c;
      float psum = 0.f;
      #pragma unroll
      for (int t = 0; t < 4; ++t) {
        lp[t * 16] = S[t][r];
        const float p = __expf(S[t][r] + bn[t * 4 + r]);
        psum += p;
        sP[wv][g * 4 + r][t * 16 + c] = __float2bfloat16(p);
      }
      lsumL[r] += psum;
    }

    const v8s pa0 = *(const v8s*)&sP[wv][c][g * 8];
    const v8s pa1 = *(const v8s*)&sP[wv][c][32 + g * 8];
    O0 = __builtin_amdgcn_mfma_f32_16x16x32_bf16(pa0, vf[0], O0, 0, 0, 0);
    O0 = __builtin_amdgcn_mfma_f32_16x16x32_bf16(pa1, vf[2], O0, 0, 0, 0);
    O1 = __builtin_amdgcn_mfma_f32_16x16x32_bf16(pa0, vf[1], O1, 0, 0, 0);
    O1 = __builtin_amdgcn_mfma_f32_16x16x32_bf16(pa1, vf[3], O1, 0, 0, 0);
  };

  v8s kfA[4], vfA[4], kfB[4], vfB[4];
  float bnA[16], bnB[16];

  loadKV(0, kfA, vfA);
  loadBias(0, bnA);
  #pragma unroll 1
  for (int kt = 0; kt < NKS / 64; kt += 2) {
    loadKV((kt + 1) * 64, kfB, vfB);
    loadBias((kt + 1) * 64, bnB);
    compute(kt * 64, kfA, vfA, bnA);
    if (kt + 2 < NKS / 64) {
      loadKV((kt + 2) * 64, kfA, vfA);
      loadBias((kt + 2) * 64, bnA);
    }
    compute((kt + 1) * 64, kfB, vfB, bnB);
  }

  // final: lsum reduce, normalize, sigmoid gate, write gated rows (bf16)
  #pragma unroll
  for (int r = 0; r < 4; ++r) {
    float rs = lsumL[r];
    rs += __shfl_xor(rs, 1);
    rs += __shfl_xor(rs, 2);
    rs += __shfl_xor(rs, 4);
    rs += __shfl_xor(rs, 8);
    const float inv = 1.0f / rs;
    const int qrow = q0 + g * 4 + r;
    const size_t gb = ((size_t)b * NQ + qrow) * 256 + h * NHD;
    const float gl0 = __bfloat162float(G[gb + c]);
    const float gl1 = __bfloat162float(G[gb + 16 + c]);
    WA[gb + c]      = __float2bfloat16(O0[r] * inv * (1.f / (1.f + __expf(-gl0))));
    WA[gb + 16 + c] = __float2bfloat16(O1[r] * inv * (1.f / (1.f + __expf(-gl1))));
  }
}

// ---------------- Kernel 3: pure MFMA output projection (WA @ Wo + b) ----------------
// 256 blocks x 4 waves; A-fragments read straight from global (WA is L2-resident).
__global__ __launch_bounds__(256) void outproj_kernel(
    const __hip_bfloat16* __restrict__ WA, const __hip_bfloat16* __restrict__ WtO,
    const float* __restrict__ output_b, float* __restrict__ out)
{
  const int t = threadIdx.x;
  const int wv = t >> 6, lane = t & 63;
  const int c = lane & 15, g = lane >> 4;
  const int r0 = blockIdx.x * 16;

  const f32x4 z = {0.f, 0.f, 0.f, 0.f};
  f32x4 ac[4] = {z, z, z, z};
  #pragma unroll
  for (int ks = 0; ks < 8; ++ks) {
    const v8s af = *(const v8s*)(WA + (size_t)(r0 + c) * 256 + ks * 32 + g * 8);
    #pragma unroll
    for (int j = 0; j < 4; ++j) {
      const v8s wf = *(const v8s*)(WtO + (size_t)((wv * 4 + j) * 16 + c) * 256 + ks * 32 + g * 8);
      ac[j] = __builtin_amdgcn_mfma_f32_16x16x32_bf16(af, wf, ac[j], 0, 0, 0);
    }
  }
  #pragma unroll
  for (int j = 0; j < 4; ++j) {
    const int o = (wv * 4 + j) * 16 + c;
    const float ob = output_b[o];
    #pragma unroll
    for (int r = 0; r < 4; ++r)
      out[(size_t)(r0 + 4 * g + r) * 256 + o] = ac[j][r] + ob;
  }
}

extern "C" void kernel_launch(void* const* d_in, const int* in_sizes, int n_in,
                              void* d_out, int out_size, void* d_ws, size_t ws_size,
                              hipStream_t stream) {
  const float* q_data   = (const float*)d_in[0];
  const float* m_data   = (const float*)d_in[1];
  const float* bias     = (const float*)d_in[2];
  const float* nbb      = (const float*)d_in[3];
  const float* query_w  = (const float*)d_in[4];
  const float* key_w    = (const float*)d_in[5];
  const float* value_w  = (const float*)d_in[6];
  const float* gating_w = (const float*)d_in[7];
  const float* gating_b = (const float*)d_in[8];
  const float* output_w = (const float*)d_in[9];
  const float* output_b = (const float*)d_in[10];

  float* out        = (float*)d_out;
  float* out_logits = out + (size_t)NB * NQ * NOUT;

  char* ws = (char*)d_ws;
  const size_t MB = 1u << 20;
  __hip_bfloat16* Qw  = (__hip_bfloat16*)(ws);              // 2MB @0
  __hip_bfloat16* Kw  = (__hip_bfloat16*)(ws + 2 * MB);     // 2MB @2
  __hip_bfloat16* Vt  = (__hip_bfloat16*)(ws + 4 * MB);     // 2MB @4
  __hip_bfloat16* G   = (__hip_bfloat16*)(ws + 6 * MB);     // 2MB @6 (bf16)
  __hip_bfloat16* Abf = (__hip_bfloat16*)(ws + 10 * MB);    // 4MB @10 (dead after proj)
  // WA aliases Abf (stream order serializes proj -> attn)
  __hip_bfloat16* WA  = (__hip_bfloat16*)(ws + 10 * MB);    // 2MB @10 (bf16, gated)
  __hip_bfloat16* Wt  = (__hip_bfloat16*)(ws + 20 * MB);    // 640KB @20 (proj + outproj)

  prep_all<<<1104, 256, 0, stream>>>(q_data, m_data, query_w, key_w, value_w,
                                     gating_w, output_w, Abf, Wt);
  proj_kernel<<<1024, 256, 0, stream>>>(Abf, Wt, gating_b, Qw, Kw, Vt, G);
  attn_kernel<<<512, 256, 0, stream>>>(Qw, Kw, Vt, bias, nbb, G, out_logits, WA);
  outproj_kernel<<<256, 256, 0, stream>>>(WA, Wt + (size_t)4 * 65536, output_b, out);
}

// Round 19
// 76.142 us; speedup vs baseline: 1.1292x; 1.0220x over previous
//
#include <hip/hip_runtime.h>
#include <hip/hip_bf16.h>

#define NB 4
#define NQ 1024
#define NKS 1024
#define ND 256
#define NH 8
#define NHD 32
#define NOUT 256

typedef __attribute__((ext_vector_type(8))) short v8s;
typedef __attribute__((ext_vector_type(4))) short v4s;
typedef __attribute__((ext_vector_type(4))) float f32x4;

// ---------------- prep: weight transpose -> bf16 [out][d] (5 matrices) ----------------
__global__ __launch_bounds__(256) void prep_w(
    const float* __restrict__ qw, const float* __restrict__ kw,
    const float* __restrict__ vw, const float* __restrict__ gw,
    const float* __restrict__ ow, __hip_bfloat16* __restrict__ Wt)
{
  __shared__ float tile[64][65];
  const int wb = blockIdx.x;                 // 0..79
  const int m = wb >> 4, bx = wb & 15;
  const float* src = (m == 0) ? qw : (m == 1) ? kw : (m == 2) ? vw
                   : (m == 3) ? gw : ow;
  const float scale = (m == 0) ? 0.1767766952966369f : 1.0f;
  const int d0 = (bx >> 2) * 64, o0 = (bx & 3) * 64;
  #pragma unroll
  for (int i = 0; i < 16; ++i) {
    const int idx = threadIdx.x + i * 256;
    tile[idx >> 6][idx & 63] = src[(size_t)(d0 + (idx >> 6)) * 256 + o0 + (idx & 63)];
  }
  __syncthreads();
  __hip_bfloat16* dst = Wt + (size_t)m * 65536;
  #pragma unroll
  for (int i = 0; i < 16; ++i) {
    const int idx = threadIdx.x + i * 256;
    const int orow = idx >> 6, dc = idx & 63;
    dst[(size_t)(o0 + orow) * 256 + d0 + dc] = __float2bfloat16(tile[dc][orow] * scale);
  }
}

// ---------------- Kernel 1: MFMA projections, LDS-staged activation conversion ----------------
// bid decode: src=bid>>9, r0g=(bid>>1)&255, mat=bid&1; the 4 waves cover ctg=wv.
// Block stages its 16 activation rows f32->bf16 in LDS ONCE (shared by 4 waves):
// removes the prep data pass + Abf ws round-trip entirely.
__global__ __launch_bounds__(256) void proj_kernel(
    const float* __restrict__ qdata, const float* __restrict__ mdata,
    const __hip_bfloat16* __restrict__ Wt, const float* __restrict__ gating_b,
    __hip_bfloat16* __restrict__ Qw, __hip_bfloat16* __restrict__ Kw,
    __hip_bfloat16* __restrict__ Vt, __hip_bfloat16* __restrict__ G)
{
  __shared__ __align__(16) __hip_bfloat16 sA[16][264];

  const int wv = threadIdx.x >> 6, lane = threadIdx.x & 63;
  const int c = lane & 15, g = lane >> 4;
  const int ctg = wv;
  const int mat = blockIdx.x & 1;
  const int r0g = (blockIdx.x >> 1) & 255;
  const int src = blockIdx.x >> 9;
  const int r0 = r0g * 16;
  const int b = r0 >> 10, pos0 = r0 & 1023;
  const f32x4 z = {0.f, 0.f, 0.f, 0.f};

  // stage 16 rows x 256 f32 -> bf16 LDS (coalesced float4 loads)
  {
    const float* A = (src ? mdata : qdata) + (size_t)r0 * 256;
    const int row = threadIdx.x >> 6, col4 = (threadIdx.x & 63) * 4;
    #pragma unroll
    for (int i = 0; i < 4; ++i) {
      const f32x4 a = *(const f32x4*)(A + (size_t)(row + i * 4) * 256 + col4);
      __hip_bfloat16 t4[4];
      t4[0] = __float2bfloat16(a.x); t4[1] = __float2bfloat16(a.y);
      t4[2] = __float2bfloat16(a.z); t4[3] = __float2bfloat16(a.w);
      *(v4s*)&sA[row + i * 4][col4] = *(v4s*)t4;
    }
  }
  __syncthreads();

  v8s af[8];
  #pragma unroll
  for (int ks = 0; ks < 8; ++ks)
    af[ks] = *(const v8s*)&sA[c][ks * 32 + g * 8];

  const int widx = (src == 0) ? (mat ? 3 : 0) : (mat ? 2 : 1);
  const __hip_bfloat16* W = Wt + (size_t)widx * 65536;
  const bool swapped = (src == 1) && (mat == 1);   // value proj -> direct Vt layout

  f32x4 ac[4] = {z, z, z, z};
  #pragma unroll
  for (int ks = 0; ks < 8; ++ks) {
    #pragma unroll
    for (int j = 0; j < 4; ++j) {
      v8s wf = *(const v8s*)(W + (size_t)((ctg * 4 + j) * 16 + c) * 256 + ks * 32 + g * 8);
      ac[j] = swapped
        ? __builtin_amdgcn_mfma_f32_16x16x32_bf16(wf, af[ks], ac[j], 0, 0, 0)
        : __builtin_amdgcn_mfma_f32_16x16x32_bf16(af[ks], wf, ac[j], 0, 0, 0);
    }
  }

  if (src == 0 && mat == 0) {          // Qw
    #pragma unroll
    for (int j = 0; j < 4; ++j) {
      const int o = (ctg * 4 + j) * 16 + c, h = o >> 5, hd = o & 31;
      #pragma unroll
      for (int r = 0; r < 4; ++r)
        Qw[((size_t)(b * NH + h) * 1024 + pos0 + 4 * g + r) * 32 + hd] =
            __float2bfloat16(ac[j][r]);
    }
  } else if (src == 0) {               // G (gating logits, bf16)
    #pragma unroll
    for (int j = 0; j < 4; ++j) {
      const int o = (ctg * 4 + j) * 16 + c;
      const float gb = gating_b[o];
      #pragma unroll
      for (int r = 0; r < 4; ++r)
        G[(size_t)(r0 + 4 * g + r) * 256 + o] = __float2bfloat16(ac[j][r] + gb);
    }
  } else if (mat == 0) {               // Kw
    #pragma unroll
    for (int j = 0; j < 4; ++j) {
      const int o = (ctg * 4 + j) * 16 + c, h = o >> 5, hd = o & 31;
      #pragma unroll
      for (int r = 0; r < 4; ++r)
        Kw[((size_t)(b * NH + h) * 1024 + pos0 + 4 * g + r) * 32 + hd] =
            __float2bfloat16(ac[j][r]);
    }
  } else {                             // Vt (swapped): coalesced over pos
    #pragma unroll
    for (int j = 0; j < 4; ++j) {
      #pragma unroll
      for (int r = 0; r < 4; ++r) {
        const int o2 = (ctg * 4 + j) * 16 + 4 * g + r;
        Vt[((size_t)(b * NH + (o2 >> 5)) * 32 + (o2 & 31)) * 1024 + pos0 + c] =
            __float2bfloat16(ac[j][r]);
      }
    }
  }
}

// ---------------- Kernel 2: flash attention, SPLIT=1, gate fused ----------------
// 512 blocks (XCD-swizzled: 4 bh per XCD, K/V L2-pinned), 4 waves/block,
// full K=1024 per wave, no partials: normalize + sigmoid-gate in-kernel,
// write final gated rows to WA (bf16). No online max (logits bounded).
__global__ __launch_bounds__(256) void attn_kernel(
    const __hip_bfloat16* __restrict__ Qw, const __hip_bfloat16* __restrict__ Kw,
    const __hip_bfloat16* __restrict__ Vt,
    const float* __restrict__ bias, const float* __restrict__ nbb,
    const __hip_bfloat16* __restrict__ G,
    float* __restrict__ out_logits, __hip_bfloat16* __restrict__ WA)
{
  __shared__ __align__(16) __hip_bfloat16 sP[4][16][72];

  const int wv = threadIdx.x >> 6, lane = threadIdx.x & 63;
  const int c = lane & 15, g = lane >> 4;
  // XCD-aware decode: bid = slot*8 + xcd; bh = ((slot>>4)<<3) | xcd
  const int xcd   = blockIdx.x & 7;
  const int slot  = blockIdx.x >> 3;          // 0..63
  const int bh    = ((slot >> 4) << 3) | xcd; // 0..31
  const int qtg   = slot & 15;
  const int qt  = qtg * 4 + wv;               // 0..63
  const int b = bh >> 3, h = bh & 7;
  const int q0 = qt * 16;
  const size_t bhs = (size_t)bh;

  const __hip_bfloat16* Kbase = Kw + bhs * NKS * NHD;
  const __hip_bfloat16* Vbase = Vt + bhs * NHD * NKS;
  const float* biasb = bias + (size_t)b * NKS;
  const float* nbbb  = nbb + ((size_t)h * NQ + q0) * NKS;

  const v8s qfrag = *(const v8s*)(Qw + (bhs * NQ + q0 + c) * NHD + g * 8);

  const f32x4 zacc = {0.f, 0.f, 0.f, 0.f};
  f32x4 O0 = zacc, O1 = zacc;
  float lsumL[4] = {0.f, 0.f, 0.f, 0.f};

  auto loadKV = [&](int k0, v8s* kf, v8s* vf) {
    kf[0] = *(const v8s*)(Kbase + (k0 +      c) * NHD + g * 8);
    kf[1] = *(const v8s*)(Kbase + (k0 + 16 + c) * NHD + g * 8);
    kf[2] = *(const v8s*)(Kbase + (k0 + 32 + c) * NHD + g * 8);
    kf[3] = *(const v8s*)(Kbase + (k0 + 48 + c) * NHD + g * 8);
    vf[0] = *(const v8s*)(Vbase + (     c) * NKS + k0 +      g * 8);
    vf[1] = *(const v8s*)(Vbase + (16 + c) * NKS + k0 +      g * 8);
    vf[2] = *(const v8s*)(Vbase + (     c) * NKS + k0 + 32 + g * 8);
    vf[3] = *(const v8s*)(Vbase + (16 + c) * NKS + k0 + 32 + g * 8);
  };
  // bn[t*4+r] = bias[col] + nbb[row][col]  (adds done at load time, off hot path)
  auto loadBias = [&](int k0, float* bn) {
    #pragma unroll
    for (int t = 0; t < 4; ++t) {
      const float bvt = biasb[k0 + t * 16 + c];
      #pragma unroll
      for (int r = 0; r < 4; ++r)
        bn[t * 4 + r] = bvt + nbbb[(g * 4 + r) * NKS + k0 + t * 16 + c];
    }
  };

  auto compute = [&](int k0, const v8s* kf, const v8s* vf, const float* bn) {
    f32x4 S[4];
    #pragma unroll
    for (int t = 0; t < 4; ++t)
      S[t] = __builtin_amdgcn_mfma_f32_16x16x32_bf16(qfrag, kf[t], zacc, 0, 0, 0);

    #pragma unroll
    for (int r = 0; r < 4; ++r) {
      const int qrow = q0 + g * 4 + r;
      float* lp = out_logits + (bhs * NQ + qrow) * (size_t)NKS + k0 + c;
      float psum = 0.f;
      #pragma unroll
      for (int t = 0; t < 4; ++t) {
        lp[t * 16] = S[t][r];
        const float p = __expf(S[t][r] + bn[t * 4 + r]);
        psum += p;
        sP[wv][g * 4 + r][t * 16 + c] = __float2bfloat16(p);
      }
      lsumL[r] += psum;
    }

    const v8s pa0 = *(const v8s*)&sP[wv][c][g * 8];
    const v8s pa1 = *(const v8s*)&sP[wv][c][32 + g * 8];
    O0 = __builtin_amdgcn_mfma_f32_16x16x32_bf16(pa0, vf[0], O0, 0, 0, 0);
    O0 = __builtin_amdgcn_mfma_f32_16x16x32_bf16(pa1, vf[2], O0, 0, 0, 0);
    O1 = __builtin_amdgcn_mfma_f32_16x16x32_bf16(pa0, vf[1], O1, 0, 0, 0);
    O1 = __builtin_amdgcn_mfma_f32_16x16x32_bf16(pa1, vf[3], O1, 0, 0, 0);
  };

  v8s kfA[4], vfA[4], kfB[4], vfB[4];
  float bnA[16], bnB[16];

  loadKV(0, kfA, vfA);
  loadBias(0, bnA);
  #pragma unroll 1
  for (int kt = 0; kt < NKS / 64; kt += 2) {
    loadKV((kt + 1) * 64, kfB, vfB);
    loadBias((kt + 1) * 64, bnB);
    compute(kt * 64, kfA, vfA, bnA);
    if (kt + 2 < NKS / 64) {
      loadKV((kt + 2) * 64, kfA, vfA);
      loadBias((kt + 2) * 64, bnA);
    }
    compute((kt + 1) * 64, kfB, vfB, bnB);
  }

  // final: lsum reduce, normalize, sigmoid gate, write gated rows (bf16)
  #pragma unroll
  for (int r = 0; r < 4; ++r) {
    float rs = lsumL[r];
    rs += __shfl_xor(rs, 1);
    rs += __shfl_xor(rs, 2);
    rs += __shfl_xor(rs, 4);
    rs += __shfl_xor(rs, 8);
    const float inv = 1.0f / rs;
    const int qrow = q0 + g * 4 + r;
    const size_t gb = ((size_t)b * NQ + qrow) * 256 + h * NHD;
    const float gl0 = __bfloat162float(G[gb + c]);
    const float gl1 = __bfloat162float(G[gb + 16 + c]);
    WA[gb + c]      = __float2bfloat16(O0[r] * inv * (1.f / (1.f + __expf(-gl0))));
    WA[gb + 16 + c] = __float2bfloat16(O1[r] * inv * (1.f / (1.f + __expf(-gl1))));
  }
}

// ---------------- Kernel 3: pure MFMA output projection (WA @ Wo + b) ----------------
__global__ __launch_bounds__(256) void outproj_kernel(
    const __hip_bfloat16* __restrict__ WA, const __hip_bfloat16* __restrict__ WtO,
    const float* __restrict__ output_b, float* __restrict__ out)
{
  const int t = threadIdx.x;
  const int wv = t >> 6, lane = t & 63;
  const int c = lane & 15, g = lane >> 4;
  const int r0 = blockIdx.x * 16;

  const f32x4 z = {0.f, 0.f, 0.f, 0.f};
  f32x4 ac[4] = {z, z, z, z};
  #pragma unroll
  for (int ks = 0; ks < 8; ++ks) {
    const v8s af = *(const v8s*)(WA + (size_t)(r0 + c) * 256 + ks * 32 + g * 8);
    #pragma unroll
    for (int j = 0; j < 4; ++j) {
      const v8s wf = *(const v8s*)(WtO + (size_t)((wv * 4 + j) * 16 + c) * 256 + ks * 32 + g * 8);
      ac[j] = __builtin_amdgcn_mfma_f32_16x16x32_bf16(af, wf, ac[j], 0, 0, 0);
    }
  }
  #pragma unroll
  for (int j = 0; j < 4; ++j) {
    const int o = (wv * 4 + j) * 16 + c;
    const float ob = output_b[o];
    #pragma unroll
    for (int r = 0; r < 4; ++r)
      out[(size_t)(r0 + 4 * g + r) * 256 + o] = ac[j][r] + ob;
  }
}

extern "C" void kernel_launch(void* const* d_in, const int* in_sizes, int n_in,
                              void* d_out, int out_size, void* d_ws, size_t ws_size,
                              hipStream_t stream) {
  const float* q_data   = (const float*)d_in[0];
  const float* m_data   = (const float*)d_in[1];
  const float* bias     = (const float*)d_in[2];
  const float* nbb      = (const float*)d_in[3];
  const float* query_w  = (const float*)d_in[4];
  const float* key_w    = (const float*)d_in[5];
  const float* value_w  = (const float*)d_in[6];
  const float* gating_w = (const float*)d_in[7];
  const float* gating_b = (const float*)d_in[8];
  const float* output_w = (const float*)d_in[9];
  const float* output_b = (const float*)d_in[10];

  float* out        = (float*)d_out;
  float* out_logits = out + (size_t)NB * NQ * NOUT;

  char* ws = (char*)d_ws;
  const size_t MB = 1u << 20;
  __hip_bfloat16* Qw  = (__hip_bfloat16*)(ws);              // 2MB @0
  __hip_bfloat16* Kw  = (__hip_bfloat16*)(ws + 2 * MB);     // 2MB @2
  __hip_bfloat16* Vt  = (__hip_bfloat16*)(ws + 4 * MB);     // 2MB @4
  __hip_bfloat16* G   = (__hip_bfloat16*)(ws + 6 * MB);     // 2MB @6 (bf16)
  __hip_bfloat16* WA  = (__hip_bfloat16*)(ws + 10 * MB);    // 2MB @10 (bf16, gated)
  __hip_bfloat16* Wt  = (__hip_bfloat16*)(ws + 20 * MB);    // 640KB @20 (proj + outproj)

  prep_w<<<80, 256, 0, stream>>>(query_w, key_w, value_w, gating_w, output_w, Wt);
  proj_kernel<<<1024, 256, 0, stream>>>(q_data, m_data, Wt, gating_b, Qw, Kw, Vt, G);
  attn_kernel<<<512, 256, 0, stream>>>(Qw, Kw, Vt, bias, nbb, G, out_logits, WA);
  outproj_kernel<<<256, 256, 0, stream>>>(WA, Wt + (size_t)4 * 65536, output_b, out);
}